// Round 2
// baseline (3518.490 us; speedup 1.0000x reference)
//
#include <hip/hip_runtime.h>
#include <math.h>

#define NR 8192
#define DDIM 128

static constexpr float LOG_AB  = -9.010913347279288f; // -ln(8192)
static constexpr float INV_EPS = 20.0f;               // 1/0.05
static constexpr float DQX     = 20.0f / 65535.0f;    // dequant -> k*INV_EPS
static constexpr float DQK     = 1.0f / 65535.0f;     // dequant -> k

// ---------------- row squared-norms: 64 lanes per row ----------------
__global__ __launch_bounds__(256) void rownorm_k(const float* __restrict__ X,
                                                 float* __restrict__ nrm) {
    const int lane = threadIdx.x & 63;
    const int w    = threadIdx.x >> 6;
    const int row  = blockIdx.x * 4 + w;
    const float2 v = *reinterpret_cast<const float2*>(&X[(size_t)row * DDIM + lane * 2]);
    float s = v.x * v.x + v.y * v.y;
#pragma unroll
    for (int off = 32; off; off >>= 1) s += __shfl_xor(s, off);
    if (lane == 0) nrm[row] = s;
}

// ---------------- GEMM + multi-scale RBF ----------------
// MODE 0: store quantized K + global max. MODE 1: sum only (symmetric: skip bn<bm, double bn>bm)
template <int MODE>
__global__ __launch_bounds__(256) void gemm_rbf_k(const float* __restrict__ A,
                                                  const float* __restrict__ B,
                                                  const float* __restrict__ na,
                                                  const float* __restrict__ nb,
                                                  unsigned short* __restrict__ K16,
                                                  unsigned* __restrict__ maxbits,
                                                  double* __restrict__ sumout) {
    const int bm = blockIdx.x, bn = blockIdx.y;
    if (MODE == 1 && bn < bm) return;
    __shared__ float As[64 * 128];   // k-major [k][m]
    __shared__ float Bs[64 * 128];   // k-major [k][n]
    const int t   = threadIdx.x;
    const int row = t & 127;
    const int kh  = t >> 7;          // 0/1
    const float* Arow = &A[(size_t)(bm * 128 + row) * DDIM];
    const float* Brow = &B[(size_t)(bn * 128 + row) * DDIM];
    const int tx = t & 15, ty = t >> 4;

    float acc[8][8];
#pragma unroll
    for (int i = 0; i < 8; ++i)
#pragma unroll
        for (int j = 0; j < 8; ++j) acc[i][j] = 0.f;

    for (int kc = 0; kc < 2; ++kc) {
        __syncthreads();
#pragma unroll
        for (int p = 0; p < 8; ++p) {
            const int k4 = kh + 2 * p;  // 0..15 within chunk
            const float4 va = *reinterpret_cast<const float4*>(&Arow[kc * 64 + k4 * 4]);
            As[(4 * k4 + 0) * 128 + row] = va.x;
            As[(4 * k4 + 1) * 128 + row] = va.y;
            As[(4 * k4 + 2) * 128 + row] = va.z;
            As[(4 * k4 + 3) * 128 + row] = va.w;
            const float4 vb = *reinterpret_cast<const float4*>(&Brow[kc * 64 + k4 * 4]);
            Bs[(4 * k4 + 0) * 128 + row] = vb.x;
            Bs[(4 * k4 + 1) * 128 + row] = vb.y;
            Bs[(4 * k4 + 2) * 128 + row] = vb.z;
            Bs[(4 * k4 + 3) * 128 + row] = vb.w;
        }
        __syncthreads();
#pragma unroll 8
        for (int k = 0; k < 64; ++k) {
            const float4 a0 = *reinterpret_cast<const float4*>(&As[k * 128 + ty * 4]);
            const float4 a1 = *reinterpret_cast<const float4*>(&As[k * 128 + 64 + ty * 4]);
            const float4 b0 = *reinterpret_cast<const float4*>(&Bs[k * 128 + tx * 4]);
            const float4 b1 = *reinterpret_cast<const float4*>(&Bs[k * 128 + 64 + tx * 4]);
            const float a[8] = {a0.x, a0.y, a0.z, a0.w, a1.x, a1.y, a1.z, a1.w};
            const float b[8] = {b0.x, b0.y, b0.z, b0.w, b1.x, b1.y, b1.z, b1.w};
#pragma unroll
            for (int i = 0; i < 8; ++i)
#pragma unroll
                for (int j = 0; j < 8; ++j) acc[i][j] = fmaf(a[i], b[j], acc[i][j]);
        }
    }

    const int m0 = bm * 128, n0 = bn * 128;
    float nbv[8];
#pragma unroll
    for (int j = 0; j < 8; ++j) nbv[j] = nb[n0 + tx * 4 + (j & 3) + (j >> 2) * 64];

    float  lmax = 0.f;
    double lsum = 0.0;
#pragma unroll
    for (int i = 0; i < 8; ++i) {
        const int   mi  = m0 + ty * 4 + (i & 3) + (i >> 2) * 64;
        const float nav = na[mi];
        float kv[8];
#pragma unroll
        for (int j = 0; j < 8; ++j) {
            float d2 = fmaf(-2.f, acc[i][j], nav + nbv[j]);
            d2 = fmaxf(d2, 0.f);
            kv[j] = 0.2f * (__expf(d2 * -0.5f) + __expf(d2 * -0.125f) +
                            __expf(d2 * -0.03125f) + __expf(d2 * -0.0078125f) +
                            __expf(d2 * -0.001953125f));
        }
        if (MODE == 0) {
            ushort4 o0, o1;
            o0.x = (unsigned short)__float2uint_rn(kv[0] * 65535.f);
            o0.y = (unsigned short)__float2uint_rn(kv[1] * 65535.f);
            o0.z = (unsigned short)__float2uint_rn(kv[2] * 65535.f);
            o0.w = (unsigned short)__float2uint_rn(kv[3] * 65535.f);
            o1.x = (unsigned short)__float2uint_rn(kv[4] * 65535.f);
            o1.y = (unsigned short)__float2uint_rn(kv[5] * 65535.f);
            o1.z = (unsigned short)__float2uint_rn(kv[6] * 65535.f);
            o1.w = (unsigned short)__float2uint_rn(kv[7] * 65535.f);
            *reinterpret_cast<ushort4*>(&K16[(size_t)mi * NR + n0 + tx * 4])      = o0;
            *reinterpret_cast<ushort4*>(&K16[(size_t)mi * NR + n0 + 64 + tx * 4]) = o1;
#pragma unroll
            for (int j = 0; j < 8; ++j) lmax = fmaxf(lmax, kv[j]);
        } else {
#pragma unroll
            for (int j = 0; j < 8; ++j) lsum += (double)kv[j];
        }
    }
    if (MODE == 0) {
#pragma unroll
        for (int off = 32; off; off >>= 1) lmax = fmaxf(lmax, __shfl_xor(lmax, off));
        if ((t & 63) == 0) atomicMax(maxbits, __float_as_uint(lmax));
    } else {
        if (bn > bm) lsum *= 2.0;
#pragma unroll
        for (int off = 32; off; off >>= 1) lsum += __shfl_xor(lsum, off);
        if ((t & 63) == 0) atomicAdd(sumout, lsum);
    }
}

// ---------------- Sinkhorn row pass: one block per row ----------------
__global__ __launch_bounds__(256) void sink_row_k(const unsigned short* __restrict__ K16,
                                                  const float* __restrict__ log_v,
                                                  float* __restrict__ log_u,
                                                  const unsigned* __restrict__ maxbits) {
    __shared__ float red[8];
    const int t = threadIdx.x;
    const size_t i = blockIdx.x;
    const float bias = -__uint_as_float(*maxbits) * INV_EPS;
    const uint4* Kr = reinterpret_cast<const uint4*>(K16 + i * NR);  // 1024 uint4/row
    const float4* Lv = reinterpret_cast<const float4*>(log_v);
    float x[32];
    float m = -1e30f;
#pragma unroll
    for (int p = 0; p < 4; ++p) {
        const int g = t + p * 256;          // uint4 index -> cols 8g..8g+7
        const uint4 w = Kr[g];
        const float4 lv0 = Lv[2 * g];
        const float4 lv1 = Lv[2 * g + 1];
        const unsigned wd[4] = {w.x, w.y, w.z, w.w};
        const float lvv[8] = {lv0.x, lv0.y, lv0.z, lv0.w, lv1.x, lv1.y, lv1.z, lv1.w};
#pragma unroll
        for (int e = 0; e < 4; ++e) {
            const float q0 = (float)(wd[e] & 0xFFFFu);
            const float q1 = (float)(wd[e] >> 16);
            const float x0 = fmaf(q0, DQX, lvv[2 * e]     + bias);
            const float x1 = fmaf(q1, DQX, lvv[2 * e + 1] + bias);
            x[p * 8 + 2 * e]     = x0;
            x[p * 8 + 2 * e + 1] = x1;
            m = fmaxf(m, fmaxf(x0, x1));
        }
    }
#pragma unroll
    for (int off = 32; off; off >>= 1) m = fmaxf(m, __shfl_xor(m, off));
    if ((t & 63) == 0) red[t >> 6] = m;
    __syncthreads();
    m = fmaxf(fmaxf(red[0], red[1]), fmaxf(red[2], red[3]));
    float s = 0.f;
#pragma unroll
    for (int q = 0; q < 32; ++q) s += __expf(x[q] - m);
#pragma unroll
    for (int off = 32; off; off >>= 1) s += __shfl_xor(s, off);
    if ((t & 63) == 0) red[4 + (t >> 6)] = s;
    __syncthreads();
    if (t == 0) {
        const float stot = (red[4] + red[5]) + (red[6] + red[7]);
        log_u[i] = LOG_AB - (m + logf(stot));
    }
}

// ---------------- Sinkhorn column pass: partial LSE over 128-row chunks ----------------
__global__ __launch_bounds__(256) void sink_colp_k(const unsigned short* __restrict__ K16,
                                                   const float* __restrict__ log_u,
                                                   float* __restrict__ pm,
                                                   float* __restrict__ ps,
                                                   const unsigned* __restrict__ maxbits) {
    const int t  = threadIdx.x;
    const int cg = blockIdx.x * 256 + t;  // uint4 col group, 0..1023 (cols 8cg..8cg+7)
    const int rc = blockIdx.y;            // row chunk, 0..63 (128 rows each)
    const float bias = -__uint_as_float(*maxbits) * INV_EPS;
    const uint4* base = reinterpret_cast<const uint4*>(K16) + (size_t)rc * 128 * 1024 + cg;
    const float* lu = log_u + rc * 128;
    float m8[8], s8[8];
#pragma unroll
    for (int e = 0; e < 8; ++e) { m8[e] = -1e30f; s8[e] = 0.f; }
    for (int r = 0; r < 128; ++r) {
        const uint4 w = base[(size_t)r * 1024];
        const float luv = lu[r] + bias;
        const unsigned wd[4] = {w.x, w.y, w.z, w.w};
#pragma unroll
        for (int e = 0; e < 4; ++e) {
            const float x0 = fmaf((float)(wd[e] & 0xFFFFu), DQX, luv);
            const float x1 = fmaf((float)(wd[e] >> 16),     DQX, luv);
            float mn;
            mn = fmaxf(m8[2 * e], x0);
            s8[2 * e] = s8[2 * e] * __expf(m8[2 * e] - mn) + __expf(x0 - mn);
            m8[2 * e] = mn;
            mn = fmaxf(m8[2 * e + 1], x1);
            s8[2 * e + 1] = s8[2 * e + 1] * __expf(m8[2 * e + 1] - mn) + __expf(x1 - mn);
            m8[2 * e + 1] = mn;
        }
    }
    float4* pmv = reinterpret_cast<float4*>(pm + (size_t)rc * NR + cg * 8);
    float4* psv = reinterpret_cast<float4*>(ps + (size_t)rc * NR + cg * 8);
    pmv[0] = {m8[0], m8[1], m8[2], m8[3]};
    pmv[1] = {m8[4], m8[5], m8[6], m8[7]};
    psv[0] = {s8[0], s8[1], s8[2], s8[3]};
    psv[1] = {s8[4], s8[5], s8[6], s8[7]};
}

__global__ __launch_bounds__(256) void sink_combine_k(const float* __restrict__ pm,
                                                      const float* __restrict__ ps,
                                                      float* __restrict__ log_v) {
    const int j = blockIdx.x * 256 + threadIdx.x;
    float m = -1e30f, s = 0.f;
#pragma unroll
    for (int c = 0; c < 64; ++c) {
        const float mc = pm[(size_t)c * NR + j];
        const float sc = ps[(size_t)c * NR + j];
        const float mn = fmaxf(m, mc);
        s = s * __expf(m - mn) + sc * __expf(mc - mn);
        m = mn;
    }
    log_v[j] = LOG_AB - (m + logf(s));
}

// ---------------- final sum(Gamma * Kxy) ----------------
__global__ __launch_bounds__(256) void gamma_sum_k(const unsigned short* __restrict__ K16,
                                                   const float* __restrict__ log_u,
                                                   const float* __restrict__ log_v,
                                                   const unsigned* __restrict__ maxbits,
                                                   double* __restrict__ S) {
    const int t  = threadIdx.x;
    const int cg = blockIdx.x * 256 + t;
    const int rc = blockIdx.y;
    const float bias = -__uint_as_float(*maxbits) * INV_EPS;
    const float4 lv0 = reinterpret_cast<const float4*>(log_v)[2 * cg];
    const float4 lv1 = reinterpret_cast<const float4*>(log_v)[2 * cg + 1];
    const float lvv[8] = {lv0.x, lv0.y, lv0.z, lv0.w, lv1.x, lv1.y, lv1.z, lv1.w};
    const uint4* base = reinterpret_cast<const uint4*>(K16) + (size_t)rc * 128 * 1024 + cg;
    const float* lu = log_u + rc * 128;
    double acc = 0.0;
    for (int r = 0; r < 128; ++r) {
        const uint4 w = base[(size_t)r * 1024];
        const float lur = lu[r] + bias;
        const unsigned wd[4] = {w.x, w.y, w.z, w.w};
        float rs = 0.f;
#pragma unroll
        for (int e = 0; e < 4; ++e) {
            const float q0 = (float)(wd[e] & 0xFFFFu);
            const float q1 = (float)(wd[e] >> 16);
            const float g0 = __expf(fmaf(q0, DQX, lur + lvv[2 * e]))     * (q0 * DQK);
            const float g1 = __expf(fmaf(q1, DQX, lur + lvv[2 * e + 1])) * (q1 * DQK);
            rs += g0 + g1;
        }
        acc += (double)rs;
    }
#pragma unroll
    for (int off = 32; off; off >>= 1) acc += __shfl_xor(acc, off);
    if ((t & 63) == 0) atomicAdd(S, acc);
}

__global__ void finalize_k(const double* __restrict__ scal, float* __restrict__ out) {
    const double inv = 1.0 / (8192.0 * 8192.0);
    out[0] = (float)(scal[1] * inv + scal[2] * inv - 2.0 * scal[3]);
}

extern "C" void kernel_launch(void* const* d_in, const int* in_sizes, int n_in,
                              void* d_out, int out_size, void* d_ws, size_t ws_size,
                              hipStream_t stream) {
    const float* X = (const float*)d_in[0];
    const float* Y = (const float*)d_in[1];

    // ---- workspace layout (total 138,543,360 B) ----
    char* ws = (char*)d_ws;
    unsigned short* K16 = (unsigned short*)ws;            // 134217728 B
    float* nx    = (float*)(ws + 134217728);              // 32 KB each
    float* ny    = nx + NR;
    float* log_u = ny + NR;
    float* log_v = log_u + NR;
    char*  scal  = (char*)(log_v + NR);                   // 256 B
    unsigned* maxbits = (unsigned*)scal;
    double*   scal_d  = (double*)scal;                    // [1]=kxx, [2]=kyy, [3]=S
    float* pm = (float*)(scal + 256);                     // 64*8192*4 = 2 MB
    float* ps = pm + 64 * NR;                             // 2 MB
    const size_t needed = 134217728 + 4 * (size_t)NR * 4 + 256 + 2 * 64 * (size_t)NR * 4;
    if (ws_size < needed) return;  // clean absmax failure instead of a GPU fault

    // zero log_u, log_v, scalars (ws is poisoned 0xAA before every call)
    hipMemsetAsync(log_u, 0, 2 * NR * sizeof(float) + 256, stream);

    rownorm_k<<<NR / 4, 256, 0, stream>>>(X, nx);
    rownorm_k<<<NR / 4, 256, 0, stream>>>(Y, ny);

    dim3 g(64, 64);
    gemm_rbf_k<0><<<g, 256, 0, stream>>>(X, Y, nx, ny, K16, maxbits, nullptr);
    gemm_rbf_k<1><<<g, 256, 0, stream>>>(X, X, nx, nx, nullptr, nullptr, scal_d + 1);
    gemm_rbf_k<1><<<g, 256, 0, stream>>>(Y, Y, ny, ny, nullptr, nullptr, scal_d + 2);

    for (int it = 0; it < 30; ++it) {
        sink_row_k<<<NR, 256, 0, stream>>>(K16, log_v, log_u, maxbits);
        sink_colp_k<<<dim3(4, 64), 256, 0, stream>>>(K16, log_u, pm, ps, maxbits);
        sink_combine_k<<<32, 256, 0, stream>>>(pm, ps, log_v);
    }

    gamma_sum_k<<<dim3(4, 64), 256, 0, stream>>>(K16, log_u, log_v, maxbits, scal_d + 3);
    finalize_k<<<1, 1, 0, stream>>>(scal_d, (float*)d_out);
}